// Round 5
// baseline (451.570 us; speedup 1.0000x reference)
//
#include <hip/hip_runtime.h>
#include <math.h>

#define BSZ 4
#define SEQ 2048
#define INDIM 32
#define DM 256
#define ED 512
#define NST 16
#define DTR 16
#define MROWS (BSZ * SEQ) /* 8192 */
#define CH 64              /* chunks for the scan */
#define LC (SEQ / CH)      /* 32 timesteps per chunk */

typedef unsigned short u16;
typedef unsigned int u32;
typedef __bf16 bf16x8 __attribute__((ext_vector_type(8)));
typedef float f32x4 __attribute__((ext_vector_type(4)));

__device__ __forceinline__ float silu_f(float x) { return x / (1.f + __expf(-x)); }

__device__ __forceinline__ u16 f2bf(float x) {
  union { float f; unsigned u; } c; c.f = x;
  return (u16)((c.u + 0x7FFF + ((c.u >> 16) & 1)) >> 16);
}
__device__ __forceinline__ float bf2f(u16 v) {
  union { unsigned u; float f; } c; c.u = ((unsigned)v) << 16;
  return c.f;
}
__device__ __forceinline__ u32 pack2(float lo, float hi) {
  return (u32)f2bf(lo) | ((u32)f2bf(hi) << 16);
}

// ---------------- bf16 MFMA GEMM, fp32 C (optional accumulate) ----------------
// 128x128 tile, 4 waves (2x2), 4x4 mfma_f32_16x16x32_bf16. M,N,K exact multiples.
template <bool ACCUM>
__global__ __launch_bounds__(256) void gemm_bf16_f32(const u16* __restrict__ A,
                                                     const u16* __restrict__ B,
                                                     float* __restrict__ C,
                                                     int M, int N, int K,
                                                     int lda, int ldc) {
  __shared__ u16 As[128][40];
  __shared__ u16 Bs[128][40];
  const int tid = threadIdx.x;
  const int m0 = blockIdx.y * 128;
  const int n0 = blockIdx.x * 128;
  const int wid = tid >> 6;
  const int lane = tid & 63;
  const int wm = (wid >> 1) * 64, wn = (wid & 1) * 64;
  const int l15 = lane & 15, l4 = lane >> 4;
  const int arow = tid >> 1;
  const int ak = (tid & 1) * 16;
  f32x4 acc[4][4];
  const f32x4 zero = {0.f, 0.f, 0.f, 0.f};
#pragma unroll
  for (int i = 0; i < 4; i++)
#pragma unroll
    for (int j = 0; j < 4; j++) acc[i][j] = zero;

  for (int k0 = 0; k0 < K; k0 += 32) {
    const u16* ap = A + (size_t)(m0 + arow) * lda + k0 + ak;
    *(int4*)&As[arow][ak]     = *(const int4*)(ap);
    *(int4*)&As[arow][ak + 8] = *(const int4*)(ap + 8);
    const u16* bp = B + (size_t)(n0 + arow) * K + k0 + ak;
    *(int4*)&Bs[arow][ak]     = *(const int4*)(bp);
    *(int4*)&Bs[arow][ak + 8] = *(const int4*)(bp + 8);
    __syncthreads();
    bf16x8 af[4], bfr[4];
#pragma unroll
    for (int i = 0; i < 4; i++) {
      af[i]  = *(const bf16x8*)&As[wm + i * 16 + l15][l4 * 8];
      bfr[i] = *(const bf16x8*)&Bs[wn + i * 16 + l15][l4 * 8];
    }
#pragma unroll
    for (int i = 0; i < 4; i++)
#pragma unroll
      for (int j = 0; j < 4; j++)
        acc[i][j] = __builtin_amdgcn_mfma_f32_16x16x32_bf16(af[i], bfr[j], acc[i][j], 0, 0, 0);
    __syncthreads();
  }
#pragma unroll
  for (int i = 0; i < 4; i++) {
    const int mb = m0 + wm + i * 16 + l4 * 4;
#pragma unroll
    for (int j = 0; j < 4; j++) {
      const int n = n0 + wn + j * 16 + l15;
      float* p = C + (size_t)mb * ldc + n;
#pragma unroll
      for (int r = 0; r < 4; r++) {
        float v = acc[i][j][r];
        if (ACCUM) v += p[(size_t)r * ldc];
        p[(size_t)r * ldc] = v;
      }
    }
  }
}

// ---------------- bf16 MFMA GEMM, u16 (bf16) C ----------------
__global__ __launch_bounds__(256) void gemm_bf16_u16(const u16* __restrict__ A,
                                                     const u16* __restrict__ B,
                                                     u16* __restrict__ C,
                                                     int M, int N, int K,
                                                     int lda, int ldc) {
  __shared__ u16 As[128][40];
  __shared__ u16 Bs[128][40];
  const int tid = threadIdx.x;
  const int m0 = blockIdx.y * 128;
  const int n0 = blockIdx.x * 128;
  const int wid = tid >> 6;
  const int lane = tid & 63;
  const int wm = (wid >> 1) * 64, wn = (wid & 1) * 64;
  const int l15 = lane & 15, l4 = lane >> 4;
  const int arow = tid >> 1;
  const int ak = (tid & 1) * 16;
  f32x4 acc[4][4];
  const f32x4 zero = {0.f, 0.f, 0.f, 0.f};
#pragma unroll
  for (int i = 0; i < 4; i++)
#pragma unroll
    for (int j = 0; j < 4; j++) acc[i][j] = zero;

  for (int k0 = 0; k0 < K; k0 += 32) {
    const u16* ap = A + (size_t)(m0 + arow) * lda + k0 + ak;
    *(int4*)&As[arow][ak]     = *(const int4*)(ap);
    *(int4*)&As[arow][ak + 8] = *(const int4*)(ap + 8);
    const u16* bp = B + (size_t)(n0 + arow) * K + k0 + ak;
    *(int4*)&Bs[arow][ak]     = *(const int4*)(bp);
    *(int4*)&Bs[arow][ak + 8] = *(const int4*)(bp + 8);
    __syncthreads();
    bf16x8 af[4], bfr[4];
#pragma unroll
    for (int i = 0; i < 4; i++) {
      af[i]  = *(const bf16x8*)&As[wm + i * 16 + l15][l4 * 8];
      bfr[i] = *(const bf16x8*)&Bs[wn + i * 16 + l15][l4 * 8];
    }
#pragma unroll
    for (int i = 0; i < 4; i++)
#pragma unroll
      for (int j = 0; j < 4; j++)
        acc[i][j] = __builtin_amdgcn_mfma_f32_16x16x32_bf16(af[i], bfr[j], acc[i][j], 0, 0, 0);
    __syncthreads();
  }
#pragma unroll
  for (int i = 0; i < 4; i++) {
    const int mb = m0 + wm + i * 16 + l4 * 4;
#pragma unroll
    for (int j = 0; j < 4; j++) {
      const int n = n0 + wn + j * 16 + l15;
      u16* p = C + (size_t)mb * ldc + n;
#pragma unroll
      for (int r = 0; r < 4; r++) p[(size_t)r * ldc] = f2bf(acc[i][j][r]);
    }
  }
}

// ---------------- fp32 NT GEMM (encoder only: K=32) ----------------
__global__ __launch_bounds__(256) void gemm_nt_enc(const float* __restrict__ A,
                                                   const float* __restrict__ B,
                                                   const float* __restrict__ bias,
                                                   float* __restrict__ C,
                                                   int M, int N, int K, int lda) {
  __shared__ float As[16][65];
  __shared__ float Bs[16][65];
  const int tid = threadIdx.x;
  const int m0 = blockIdx.y * 64;
  const int n0 = blockIdx.x * 64;
  const int tm = tid & 15, tn = tid >> 4;
  const int lrow = tid >> 2;
  const int lk = (tid & 3) << 2;
  float acc[4][4] = {};
  for (int k0 = 0; k0 < K; k0 += 16) {
    {
      const float4 a = *(const float4*)(A + (size_t)(m0 + lrow) * lda + k0 + lk);
      As[lk + 0][lrow] = a.x; As[lk + 1][lrow] = a.y;
      As[lk + 2][lrow] = a.z; As[lk + 3][lrow] = a.w;
    }
    {
      float4 b = make_float4(0.f, 0.f, 0.f, 0.f);
      if (n0 + lrow < N) b = *(const float4*)(B + (size_t)(n0 + lrow) * K + k0 + lk);
      Bs[lk + 0][lrow] = b.x; Bs[lk + 1][lrow] = b.y;
      Bs[lk + 2][lrow] = b.z; Bs[lk + 3][lrow] = b.w;
    }
    __syncthreads();
#pragma unroll
    for (int k = 0; k < 16; k++) {
      float a4[4], b4[4];
#pragma unroll
      for (int i = 0; i < 4; i++) a4[i] = As[k][tm * 4 + i];
#pragma unroll
      for (int j = 0; j < 4; j++) b4[j] = Bs[k][tn * 4 + j];
#pragma unroll
      for (int i = 0; i < 4; i++)
#pragma unroll
        for (int j = 0; j < 4; j++) acc[i][j] = fmaf(a4[i], b4[j], acc[i][j]);
    }
    __syncthreads();
  }
#pragma unroll
  for (int i = 0; i < 4; i++) {
    const int m = m0 + tm * 4 + i;
#pragma unroll
    for (int j = 0; j < 4; j++) {
      const int n = n0 + tn * 4 + j;
      if (n < N) C[(size_t)m * N + n] = acc[i][j] + bias[n];
    }
  }
}

// ---------------- weight fp32 -> bf16 conversion ----------------
#define S_IN (2 * 1024 * 256)
#define S_OUT (2 * 256 * 512)
#define S_XP (2 * 48 * 512)
__global__ __launch_bounds__(256) void cvt_weights_k(const float* __restrict__ w1,
                                                     const float* __restrict__ w2,
                                                     const float* __restrict__ w3,
                                                     u16* __restrict__ o1,
                                                     u16* __restrict__ o2,
                                                     u16* __restrict__ o3) {
  const int i = blockIdx.x * 256 + threadIdx.x;
  if (i < S_IN) o1[i] = f2bf(w1[i]);
  else if (i < S_IN + S_OUT) o2[i - S_IN] = f2bf(w2[i - S_IN]);
  else if (i < S_IN + S_OUT + S_XP) o3[i - S_IN - S_OUT] = f2bf(w3[i - S_IN - S_OUT]);
}

// ---------------- rmsnorm over DM=256, bf16 output ----------------
__global__ __launch_bounds__(256) void rmsnorm_k(const float* __restrict__ h,
                                                 const float* __restrict__ w,
                                                 u16* __restrict__ out16) {
  __shared__ float sh[4];
  __shared__ float sscale;
  const int row = blockIdx.x;
  const int tid = threadIdx.x;
  const float v = h[(size_t)row * DM + tid];
  float s = v * v;
#pragma unroll
  for (int off = 32; off; off >>= 1) s += __shfl_xor(s, off, 64);
  if ((tid & 63) == 0) sh[tid >> 6] = s;
  __syncthreads();
  if (tid == 0) {
    float t = sh[0] + sh[1] + sh[2] + sh[3];
    sscale = rsqrtf(t * (1.0f / DM) + 1e-5f);
  }
  __syncthreads();
  out16[(size_t)row * DM + tid] = f2bf(v * sscale * w[tid]);
}

// ======= fused conv_silu + x_proj GEMM + dt_softplus =======
// grid: 128 blocks, each owns 64 consecutive rows (never crossing batch).
// Outputs: xbc16[row][e] (conv result), BC[row][32] (B,C fp32),
//          pairs[row][e] = pack(delta, delta*x) bf16x2.
__global__ __launch_bounds__(256) void fused_cxd(const u16* __restrict__ xz16,
                                                 const float* __restrict__ cw,
                                                 const float* __restrict__ cb,
                                                 const u16* __restrict__ wxp_g,
                                                 const float* __restrict__ dtw,
                                                 const float* __restrict__ dtb,
                                                 u16* __restrict__ xbc16,
                                                 float* __restrict__ BC,
                                                 u32* __restrict__ pairs) {
  __shared__ u16 xraw[67][72];
  __shared__ u16 xc[64][72];
  __shared__ u16 wxp[48][72];
  __shared__ float dbcs[64][48];
  const int tid = threadIdx.x;
  const int row0 = blockIdx.x * 64;
  const int t0 = row0 & (SEQ - 1);
  const int wid = tid >> 6;
  const int lane = tid & 63;
  const int l15 = lane & 15, l4 = lane >> 4;
  f32x4 acc[3];
  const f32x4 zero = {0.f, 0.f, 0.f, 0.f};
  acc[0] = zero; acc[1] = zero; acc[2] = zero;

  const int el = tid & 63;
  const int tq = tid >> 6;

  for (int kc = 0; kc < 8; kc++) {
    const int e0 = kc * 64;
    __syncthreads();
    // stage raw x rows (t0-3 .. t0+63) and x_proj weight chunk
    for (int idx = tid; idx < 67 * 8; idx += 256) {
      const int r = idx >> 3, kk = (idx & 7) * 8;
      int4 v = {0, 0, 0, 0};
      if (t0 != 0 || r >= 3)
        v = *(const int4*)(xz16 + (size_t)(row0 - 3 + r) * 1024 + e0 + kk);
      *(int4*)&xraw[r][kk] = v;
    }
    for (int idx = tid; idx < 48 * 8; idx += 256) {
      const int r = idx >> 3, kk = (idx & 7) * 8;
      *(int4*)&wxp[r][kk] = *(const int4*)(wxp_g + (size_t)r * ED + e0 + kk);
    }
    __syncthreads();
    // causal depthwise conv + silu for this 64-e chunk
    {
      const float4 w = *(const float4*)(cw + (e0 + el) * 4);
      const float bias = cb[e0 + el];
#pragma unroll
      for (int tt = 0; tt < 16; tt++) {
        const int t = tq * 16 + tt;
        float a = bias;
        a = fmaf(bf2f(xraw[t + 0][el]), w.x, a);
        a = fmaf(bf2f(xraw[t + 1][el]), w.y, a);
        a = fmaf(bf2f(xraw[t + 2][el]), w.z, a);
        a = fmaf(bf2f(xraw[t + 3][el]), w.w, a);
        const u16 vb = f2bf(silu_f(a));
        xc[t][el] = vb;
        xbc16[(size_t)(row0 + t) * ED + e0 + el] = vb;
      }
    }
    __syncthreads();
    // MFMA: wave wid owns m-rows [16*wid, +16), 3 n-tiles of 16 (48 cols)
#pragma unroll
    for (int half = 0; half < 2; half++) {
      const bf16x8 af = *(const bf16x8*)&xc[16 * wid + l15][half * 32 + l4 * 8];
#pragma unroll
      for (int j = 0; j < 3; j++) {
        const bf16x8 bfr = *(const bf16x8*)&wxp[16 * j + l15][half * 32 + l4 * 8];
        acc[j] = __builtin_amdgcn_mfma_f32_16x16x32_bf16(af, bfr, acc[j], 0, 0, 0);
      }
    }
  }
  __syncthreads();
  // spill dbc tile to LDS
#pragma unroll
  for (int j = 0; j < 3; j++)
#pragma unroll
    for (int r = 0; r < 4; r++)
      dbcs[16 * wid + l4 * 4 + r][16 * j + l15] = acc[j][r];
  __syncthreads();
  // write B,C (cols 16..47) to global
  for (int idx = tid; idx < 64 * 32; idx += 256) {
    const int t = idx >> 5, jj = idx & 31;
    BC[(size_t)(row0 + t) * 32 + jj] = dbcs[t][16 + jj];
  }
  // dt: delta = softplus(dbc[:, :16] @ dtw^T + dtb); pairs = (delta, delta*x)
#pragma unroll
  for (int eo = 0; eo < 2; eo++) {
    const int e = eo * 256 + tid;
    const float4 w0 = *(const float4*)(dtw + (size_t)e * 16 + 0);
    const float4 w1 = *(const float4*)(dtw + (size_t)e * 16 + 4);
    const float4 w2 = *(const float4*)(dtw + (size_t)e * 16 + 8);
    const float4 w3 = *(const float4*)(dtw + (size_t)e * 16 + 12);
    const float bias = dtb[e];
    for (int t = 0; t < 64; t++) {
      const float4 d0 = *(const float4*)&dbcs[t][0];
      const float4 d1 = *(const float4*)&dbcs[t][4];
      const float4 d2 = *(const float4*)&dbcs[t][8];
      const float4 d3 = *(const float4*)&dbcs[t][12];
      float s = bias;
      s = fmaf(d0.x, w0.x, s); s = fmaf(d0.y, w0.y, s);
      s = fmaf(d0.z, w0.z, s); s = fmaf(d0.w, w0.w, s);
      s = fmaf(d1.x, w1.x, s); s = fmaf(d1.y, w1.y, s);
      s = fmaf(d1.z, w1.z, s); s = fmaf(d1.w, w1.w, s);
      s = fmaf(d2.x, w2.x, s); s = fmaf(d2.y, w2.y, s);
      s = fmaf(d2.z, w2.z, s); s = fmaf(d2.w, w2.w, s);
      s = fmaf(d3.x, w3.x, s); s = fmaf(d3.y, w3.y, s);
      s = fmaf(d3.z, w3.z, s); s = fmaf(d3.w, w3.w, s);
      const float sp = fmaxf(s, 0.f) + log1pf(__expf(-fabsf(s)));
      const float xv = bf2f(xbc16[(size_t)(row0 + t) * ED + e]);
      pairs[(size_t)(row0 + t) * ED + e] = pack2(sp, sp * xv);
    }
  }
}

// ================= chunked selective scan =================
// pass1: local scan from h=0 -> hend16 (bf16), S=sum(delta) -> Sbuf.
__global__ __launch_bounds__(256) void scan_pass1(const u32* __restrict__ pairs,
                                                  const float* __restrict__ BC,
                                                  u16* __restrict__ hend16,
                                                  float* __restrict__ Sbuf,
                                                  const float* __restrict__ A_log) {
  __shared__ float sB[LC][16];
  const int tid = threadIdx.x;
  const int e = blockIdx.x * 256 + tid;
  const int c = blockIdx.y;
  const int b = blockIdx.z;
  const int row0 = b * SEQ + c * LC;
  float Aen[16];
  {
    const float4* ap = (const float4*)(A_log + (size_t)e * 16);
#pragma unroll
    for (int q = 0; q < 4; q++) {
      float4 v = ap[q];
      Aen[4 * q + 0] = -__expf(v.x); Aen[4 * q + 1] = -__expf(v.y);
      Aen[4 * q + 2] = -__expf(v.z); Aen[4 * q + 3] = -__expf(v.w);
    }
  }
  for (int idx = tid; idx < LC * 16; idx += 256)
    sB[idx >> 4][idx & 15] = BC[(size_t)(row0 + (idx >> 4)) * 32 + (idx & 15)];
  __syncthreads();
  const u32* pp = pairs + (size_t)row0 * ED + e;
  float h[16];
#pragma unroll
  for (int n = 0; n < 16; n++) h[n] = 0.f;
  float S = 0.f;
  u32 p = pp[0];
  for (int t = 0; t < LC; t++) {
    const u32 pn = (t + 1 < LC) ? pp[(size_t)(t + 1) * ED] : p;
    const float d = bf2f((u16)(p & 0xffff));
    const float dx = bf2f((u16)(p >> 16));
    S += d;
    const float4* bp = (const float4*)sB[t];
    const float4 B0 = bp[0], B1 = bp[1], B2 = bp[2], B3 = bp[3];
    const float Bv[16] = {B0.x, B0.y, B0.z, B0.w, B1.x, B1.y, B1.z, B1.w,
                          B2.x, B2.y, B2.z, B2.w, B3.x, B3.y, B3.z, B3.w};
#pragma unroll
    for (int n = 0; n < 16; n++) h[n] = __expf(d * Aen[n]) * h[n] + dx * Bv[n];
    p = pn;
  }
  u32 wbuf[8];
#pragma unroll
  for (int q = 0; q < 8; q++) wbuf[q] = pack2(h[2 * q], h[2 * q + 1]);
  u16* hp = hend16 + ((size_t)(c * BSZ + b) * ED + e) * 16;
  *(int4*)(hp) = *(int4*)&wbuf[0];
  *(int4*)(hp + 8) = *(int4*)&wbuf[4];
  Sbuf[(size_t)(c * BSZ + b) * ED + e] = S;
}

// mid: sequential over chunks; hend16 -> hin (exclusive prefix) in place.
__global__ __launch_bounds__(256) void scan_mid(u16* __restrict__ hend16,
                                                const float* __restrict__ Sbuf,
                                                const float* __restrict__ A_log) {
  const int idx = blockIdx.x * 256 + threadIdx.x; // B*ED*NST = 32768
  const int en = idx & 8191;
  const int b = idx >> 13;
  const int e = en >> 4;
  const float A = -__expf(A_log[en]);
  float h = 0.f;
#pragma unroll 4
  for (int c = 0; c < CH; c++) {
    const size_t base = (size_t)(c * BSZ + b) * 8192 + en;
    const float he = bf2f(hend16[base]);
    const float Sv = Sbuf[(size_t)(c * BSZ + b) * ED + e];
    hend16[base] = f2bf(h);
    h = __expf(A * Sv) * h + he;
  }
}

// pass2: re-scan from hin; y = C.h + D*x, gated by silu(z); y (bf16) -> xz x-half.
__global__ __launch_bounds__(256) void scan_pass2(const u32* __restrict__ pairs,
                                                  const u16* __restrict__ xbc16,
                                                  const float* __restrict__ BC,
                                                  u16* __restrict__ xz16,
                                                  const u16* __restrict__ hin16,
                                                  const float* __restrict__ A_log,
                                                  const float* __restrict__ Dp) {
  __shared__ float sB[LC][16];
  __shared__ float sC[LC][16];
  const int tid = threadIdx.x;
  const int e = blockIdx.x * 256 + tid;
  const int c = blockIdx.y;
  const int b = blockIdx.z;
  const int row0 = b * SEQ + c * LC;
  float Aen[16];
  {
    const float4* ap = (const float4*)(A_log + (size_t)e * 16);
#pragma unroll
    for (int q = 0; q < 4; q++) {
      float4 v = ap[q];
      Aen[4 * q + 0] = -__expf(v.x); Aen[4 * q + 1] = -__expf(v.y);
      Aen[4 * q + 2] = -__expf(v.z); Aen[4 * q + 3] = -__expf(v.w);
    }
  }
  for (int idx = tid; idx < LC * 32; idx += 256) {
    const int i = idx >> 5, jj = idx & 31;
    const float v = BC[(size_t)(row0 + i) * 32 + jj];
    if (jj < 16) sB[i][jj] = v; else sC[i][jj - 16] = v;
  }
  __syncthreads();
  float h[16];
  {
    const u16* hp = hin16 + ((size_t)(c * BSZ + b) * ED + e) * 16;
    int4 v0 = *(const int4*)(hp);
    int4 v1 = *(const int4*)(hp + 8);
    const u32* wv = (const u32*)&v0;
    const u32* wv1 = (const u32*)&v1;
#pragma unroll
    for (int q = 0; q < 4; q++) {
      h[2 * q] = bf2f((u16)(wv[q] & 0xffff));
      h[2 * q + 1] = bf2f((u16)(wv[q] >> 16));
      h[8 + 2 * q] = bf2f((u16)(wv1[q] & 0xffff));
      h[8 + 2 * q + 1] = bf2f((u16)(wv1[q] >> 16));
    }
  }
  const float De = Dp[e];
  const u32* pp = pairs + (size_t)row0 * ED + e;
  const u16* xp = xbc16 + (size_t)row0 * ED + e;
  const u16* zp = xz16 + (size_t)row0 * 1024 + ED + e;
  u16* yw = xz16 + (size_t)row0 * 1024 + e;
  u32 p = pp[0];
  float xv = bf2f(xp[0]);
  float zv = bf2f(zp[0]);
  for (int t = 0; t < LC; t++) {
    const int tn = (t + 1 < LC) ? t + 1 : t;
    const u32 pn = pp[(size_t)tn * ED];
    const float xnx = bf2f(xp[(size_t)tn * ED]);
    const float znx = bf2f(zp[(size_t)tn * 1024]);
    const float d = bf2f((u16)(p & 0xffff));
    const float dx = bf2f((u16)(p >> 16));
    const float4* bp = (const float4*)sB[t];
    const float4 B0 = bp[0], B1 = bp[1], B2 = bp[2], B3 = bp[3];
    const float Bv[16] = {B0.x, B0.y, B0.z, B0.w, B1.x, B1.y, B1.z, B1.w,
                          B2.x, B2.y, B2.z, B2.w, B3.x, B3.y, B3.z, B3.w};
    const float4* cp = (const float4*)sC[t];
    const float4 C0 = cp[0], C1 = cp[1], C2 = cp[2], C3 = cp[3];
    const float Cv[16] = {C0.x, C0.y, C0.z, C0.w, C1.x, C1.y, C1.z, C1.w,
                          C2.x, C2.y, C2.z, C2.w, C3.x, C3.y, C3.z, C3.w};
    float y0 = 0.f, y1 = 0.f, y2 = 0.f, y3 = 0.f;
#pragma unroll
    for (int n = 0; n < 16; n++) {
      h[n] = __expf(d * Aen[n]) * h[n] + dx * Bv[n];
      if ((n & 3) == 0) y0 = fmaf(h[n], Cv[n], y0);
      else if ((n & 3) == 1) y1 = fmaf(h[n], Cv[n], y1);
      else if ((n & 3) == 2) y2 = fmaf(h[n], Cv[n], y2);
      else y3 = fmaf(h[n], Cv[n], y3);
    }
    float y = ((y0 + y1) + (y2 + y3)) + De * xv;
    y *= silu_f(zv);
    yw[(size_t)t * 1024] = f2bf(y);
    p = pn; xv = xnx; zv = znx;
  }
}

// ---------------- final decode ----------------
__global__ __launch_bounds__(64) void decode_k(const float* __restrict__ h,
                                               const float* __restrict__ dw,
                                               const float* __restrict__ db,
                                               float* __restrict__ out) {
  const int b = blockIdx.x;
  const int tid = threadIdx.x;
  const float* row = h + ((size_t)b * SEQ + SEQ - 1) * DM;
  float s = 0.f;
  for (int i = tid; i < DM; i += 64) s = fmaf(row[i], dw[i], s);
#pragma unroll
  for (int off = 32; off; off >>= 1) s += __shfl_xor(s, off, 64);
  if (tid == 0) out[b] = 1.f / (1.f + __expf(-(s + db[0])));
}

extern "C" void kernel_launch(void* const* d_in, const int* in_sizes, int n_in,
                              void* d_out, int out_size, void* d_ws, size_t ws_size,
                              hipStream_t stream) {
  const float* x         = (const float*)d_in[0];
  const float* enc_w     = (const float*)d_in[1];
  const float* enc_b     = (const float*)d_in[2];
  const float* norm_w    = (const float*)d_in[3];
  const float* in_proj_w = (const float*)d_in[4];
  const float* conv_w    = (const float*)d_in[5];
  const float* conv_b    = (const float*)d_in[6];
  const float* x_proj_w  = (const float*)d_in[7];
  const float* dt_proj_w = (const float*)d_in[8];
  const float* dt_proj_b = (const float*)d_in[9];
  const float* A_log     = (const float*)d_in[10];
  const float* D_param   = (const float*)d_in[11];
  const float* out_proj_w= (const float*)d_in[12];
  const float* dec_w     = (const float*)d_in[13];
  const float* dec_b     = (const float*)d_in[14];
  float* out = (float*)d_out;

  float* ws = (float*)d_ws;
  float* h       = ws;                         // 2,097,152 f32
  u16*   xz16    = (u16*)(ws + 2097152);       // 8M u16 (4M slots)
  u16*   xbc16   = (u16*)(ws + 6291456);       // 4M u16 (2M slots)
  u32*   pairs   = (u32*)(ws + 8388608);       // 4M u32 (4M slots)
  float* BC      = ws + 12582912;              // 262,144 f32
  u16*   hend16  = (u16*)(ws + 12845056);      // 2M u16 (1M slots)
  float* Sbuf    = ws + 13893632;              // 131,072 f32
  u16*   w16in   = (u16*)(ws + 14024704);      // 524,288 u16
  u16*   w16out  = (u16*)(ws + 14286848);      // 262,144 u16
  u16*   w16xp   = (u16*)(ws + 14417920);      // 49,152 u16
  u16*   normed16 = hend16;                    // aliased: disjoint lifetimes

  const dim3 blk(256);

  cvt_weights_k<<<(S_IN + S_OUT + S_XP + 255) / 256, blk, 0, stream>>>(
      in_proj_w, out_proj_w, x_proj_w, w16in, w16out, w16xp);

  gemm_nt_enc<<<dim3(DM / 64, MROWS / 64), blk, 0, stream>>>(
      x, enc_w, enc_b, h, MROWS, DM, INDIM, INDIM);

  for (int l = 0; l < 2; l++) {
    const float* Al = A_log + (size_t)l * ED * NST;
    rmsnorm_k<<<MROWS, 256, 0, stream>>>(h, norm_w + (size_t)l * DM, normed16);
    gemm_bf16_u16<<<dim3(1024 / 128, MROWS / 128), blk, 0, stream>>>(
        normed16, w16in + (size_t)l * 1024 * DM, xz16, MROWS, 1024, DM, DM, 1024);
    fused_cxd<<<MROWS / 64, blk, 0, stream>>>(
        xz16, conv_w + (size_t)l * ED * 4, conv_b + (size_t)l * ED,
        w16xp + (size_t)l * 48 * ED, dt_proj_w + (size_t)l * ED * DTR,
        dt_proj_b + (size_t)l * ED, xbc16, BC, pairs);
    scan_pass1<<<dim3(ED / 256, CH, BSZ), blk, 0, stream>>>(
        pairs, BC, hend16, Sbuf, Al);
    scan_mid<<<(BSZ * ED * NST) / 256, blk, 0, stream>>>(hend16, Sbuf, Al);
    scan_pass2<<<dim3(ED / 256, CH, BSZ), blk, 0, stream>>>(
        pairs, xbc16, BC, xz16, hend16, Al, D_param + (size_t)l * ED);
    gemm_bf16_f32<true><<<dim3(DM / 128, MROWS / 128), blk, 0, stream>>>(
        xz16, w16out + (size_t)l * DM * ED, h, MROWS, DM, ED, 1024, DM);
  }

  decode_k<<<4, 64, 0, stream>>>(h, dec_w, dec_b, out);
}

// Round 6
// 394.790 us; speedup vs baseline: 1.1438x; 1.1438x over previous
//
#include <hip/hip_runtime.h>
#include <math.h>

#define BSZ 4
#define SEQ 2048
#define INDIM 32
#define DM 256
#define ED 512
#define NST 16
#define DTR 16
#define MROWS (BSZ * SEQ) /* 8192 */
#define CH 64              /* chunks for the scan */
#define LC (SEQ / CH)      /* 32 timesteps per chunk */

typedef unsigned short u16;
typedef unsigned int u32;
typedef __bf16 bf16x8 __attribute__((ext_vector_type(8)));
typedef float f32x4 __attribute__((ext_vector_type(4)));

__device__ __forceinline__ float silu_f(float x) { return x / (1.f + __expf(-x)); }

__device__ __forceinline__ u16 f2bf(float x) {
  union { float f; unsigned u; } c; c.f = x;
  return (u16)((c.u + 0x7FFF + ((c.u >> 16) & 1)) >> 16);
}
__device__ __forceinline__ float bf2f(u16 v) {
  union { unsigned u; float f; } c; c.u = ((unsigned)v) << 16;
  return c.f;
}
__device__ __forceinline__ u32 pack2(float lo, float hi) {
  return (u32)f2bf(lo) | ((u32)f2bf(hi) << 16);
}

// ---------------- bf16 MFMA GEMM, fp32 C, N-guarded (xproj / outproj) ----------------
template <bool ACCUM>
__global__ __launch_bounds__(256) void gemm_bf16_f32(const u16* __restrict__ A,
                                                     const u16* __restrict__ B,
                                                     float* __restrict__ C,
                                                     int M, int N, int K,
                                                     int lda, int ldc) {
  __shared__ u16 As[128][40];
  __shared__ u16 Bs[128][40];
  const int tid = threadIdx.x;
  const int m0 = blockIdx.y * 128;
  const int n0 = blockIdx.x * 128;
  const int wid = tid >> 6;
  const int lane = tid & 63;
  const int wm = (wid >> 1) * 64, wn = (wid & 1) * 64;
  const int l15 = lane & 15, l4 = lane >> 4;
  const int arow = tid >> 1;
  const int ak = (tid & 1) * 16;
  f32x4 acc[4][4];
  const f32x4 zero = {0.f, 0.f, 0.f, 0.f};
#pragma unroll
  for (int i = 0; i < 4; i++)
#pragma unroll
    for (int j = 0; j < 4; j++) acc[i][j] = zero;

  for (int k0 = 0; k0 < K; k0 += 32) {
    const u16* ap = A + (size_t)(m0 + arow) * lda + k0 + ak;
    *(int4*)&As[arow][ak]     = *(const int4*)(ap);
    *(int4*)&As[arow][ak + 8] = *(const int4*)(ap + 8);
    int4 bv0 = {0, 0, 0, 0}, bv1 = {0, 0, 0, 0};
    if (n0 + arow < N) {
      const u16* bp = B + (size_t)(n0 + arow) * K + k0 + ak;
      bv0 = *(const int4*)(bp);
      bv1 = *(const int4*)(bp + 8);
    }
    *(int4*)&Bs[arow][ak]     = bv0;
    *(int4*)&Bs[arow][ak + 8] = bv1;
    __syncthreads();
    bf16x8 af[4], bfr[4];
#pragma unroll
    for (int i = 0; i < 4; i++) {
      af[i]  = *(const bf16x8*)&As[wm + i * 16 + l15][l4 * 8];
      bfr[i] = *(const bf16x8*)&Bs[wn + i * 16 + l15][l4 * 8];
    }
#pragma unroll
    for (int i = 0; i < 4; i++)
#pragma unroll
      for (int j = 0; j < 4; j++)
        acc[i][j] = __builtin_amdgcn_mfma_f32_16x16x32_bf16(af[i], bfr[j], acc[i][j], 0, 0, 0);
    __syncthreads();
  }
#pragma unroll
  for (int i = 0; i < 4; i++) {
    const int mb = m0 + wm + i * 16 + l4 * 4;
#pragma unroll
    for (int j = 0; j < 4; j++) {
      const int n = n0 + wn + j * 16 + l15;
      if (n < N) {
        float* p = C + (size_t)mb * ldc + n;
#pragma unroll
        for (int r = 0; r < 4; r++) {
          float v = acc[i][j][r];
          if (ACCUM) v += p[(size_t)r * ldc];
          p[(size_t)r * ldc] = v;
        }
      }
    }
  }
}

// ---------------- bf16 MFMA GEMM, u16 C (in_proj; exact multiples) ----------------
__global__ __launch_bounds__(256) void gemm_bf16_u16(const u16* __restrict__ A,
                                                     const u16* __restrict__ B,
                                                     u16* __restrict__ C,
                                                     int M, int N, int K,
                                                     int lda, int ldc) {
  __shared__ u16 As[128][40];
  __shared__ u16 Bs[128][40];
  const int tid = threadIdx.x;
  const int m0 = blockIdx.y * 128;
  const int n0 = blockIdx.x * 128;
  const int wid = tid >> 6;
  const int lane = tid & 63;
  const int wm = (wid >> 1) * 64, wn = (wid & 1) * 64;
  const int l15 = lane & 15, l4 = lane >> 4;
  const int arow = tid >> 1;
  const int ak = (tid & 1) * 16;
  f32x4 acc[4][4];
  const f32x4 zero = {0.f, 0.f, 0.f, 0.f};
#pragma unroll
  for (int i = 0; i < 4; i++)
#pragma unroll
    for (int j = 0; j < 4; j++) acc[i][j] = zero;

  for (int k0 = 0; k0 < K; k0 += 32) {
    const u16* ap = A + (size_t)(m0 + arow) * lda + k0 + ak;
    *(int4*)&As[arow][ak]     = *(const int4*)(ap);
    *(int4*)&As[arow][ak + 8] = *(const int4*)(ap + 8);
    const u16* bp = B + (size_t)(n0 + arow) * K + k0 + ak;
    *(int4*)&Bs[arow][ak]     = *(const int4*)(bp);
    *(int4*)&Bs[arow][ak + 8] = *(const int4*)(bp + 8);
    __syncthreads();
    bf16x8 af[4], bfr[4];
#pragma unroll
    for (int i = 0; i < 4; i++) {
      af[i]  = *(const bf16x8*)&As[wm + i * 16 + l15][l4 * 8];
      bfr[i] = *(const bf16x8*)&Bs[wn + i * 16 + l15][l4 * 8];
    }
#pragma unroll
    for (int i = 0; i < 4; i++)
#pragma unroll
      for (int j = 0; j < 4; j++)
        acc[i][j] = __builtin_amdgcn_mfma_f32_16x16x32_bf16(af[i], bfr[j], acc[i][j], 0, 0, 0);
    __syncthreads();
  }
#pragma unroll
  for (int i = 0; i < 4; i++) {
    const int mb = m0 + wm + i * 16 + l4 * 4;
#pragma unroll
    for (int j = 0; j < 4; j++) {
      const int n = n0 + wn + j * 16 + l15;
      u16* p = C + (size_t)mb * ldc + n;
#pragma unroll
      for (int r = 0; r < 4; r++) p[(size_t)r * ldc] = f2bf(acc[i][j][r]);
    }
  }
}

// ---------------- fp32 NT GEMM (encoder only: K=32) ----------------
__global__ __launch_bounds__(256) void gemm_nt_enc(const float* __restrict__ A,
                                                   const float* __restrict__ B,
                                                   const float* __restrict__ bias,
                                                   float* __restrict__ C,
                                                   int M, int N, int K, int lda) {
  __shared__ float As[16][65];
  __shared__ float Bs[16][65];
  const int tid = threadIdx.x;
  const int m0 = blockIdx.y * 64;
  const int n0 = blockIdx.x * 64;
  const int tm = tid & 15, tn = tid >> 4;
  const int lrow = tid >> 2;
  const int lk = (tid & 3) << 2;
  float acc[4][4] = {};
  for (int k0 = 0; k0 < K; k0 += 16) {
    {
      const float4 a = *(const float4*)(A + (size_t)(m0 + lrow) * lda + k0 + lk);
      As[lk + 0][lrow] = a.x; As[lk + 1][lrow] = a.y;
      As[lk + 2][lrow] = a.z; As[lk + 3][lrow] = a.w;
    }
    {
      float4 b = make_float4(0.f, 0.f, 0.f, 0.f);
      if (n0 + lrow < N) b = *(const float4*)(B + (size_t)(n0 + lrow) * K + k0 + lk);
      Bs[lk + 0][lrow] = b.x; Bs[lk + 1][lrow] = b.y;
      Bs[lk + 2][lrow] = b.z; Bs[lk + 3][lrow] = b.w;
    }
    __syncthreads();
#pragma unroll
    for (int k = 0; k < 16; k++) {
      float a4[4], b4[4];
#pragma unroll
      for (int i = 0; i < 4; i++) a4[i] = As[k][tm * 4 + i];
#pragma unroll
      for (int j = 0; j < 4; j++) b4[j] = Bs[k][tn * 4 + j];
#pragma unroll
      for (int i = 0; i < 4; i++)
#pragma unroll
        for (int j = 0; j < 4; j++) acc[i][j] = fmaf(a4[i], b4[j], acc[i][j]);
    }
    __syncthreads();
  }
#pragma unroll
  for (int i = 0; i < 4; i++) {
    const int m = m0 + tm * 4 + i;
#pragma unroll
    for (int j = 0; j < 4; j++) {
      const int n = n0 + tn * 4 + j;
      if (n < N) C[(size_t)m * N + n] = acc[i][j] + bias[n];
    }
  }
}

// ---------------- weight fp32 -> bf16 conversion ----------------
#define S_IN (2 * 1024 * 256)
#define S_OUT (2 * 256 * 512)
#define S_XP (2 * 48 * 512)
__global__ __launch_bounds__(256) void cvt_weights_k(const float* __restrict__ w1,
                                                     const float* __restrict__ w2,
                                                     const float* __restrict__ w3,
                                                     u16* __restrict__ o1,
                                                     u16* __restrict__ o2,
                                                     u16* __restrict__ o3) {
  const int i = blockIdx.x * 256 + threadIdx.x;
  if (i < S_IN) o1[i] = f2bf(w1[i]);
  else if (i < S_IN + S_OUT) o2[i - S_IN] = f2bf(w2[i - S_IN]);
  else if (i < S_IN + S_OUT + S_XP) o3[i - S_IN - S_OUT] = f2bf(w3[i - S_IN - S_OUT]);
}

// ---------------- rmsnorm over DM=256, bf16 output ----------------
__global__ __launch_bounds__(256) void rmsnorm_k(const float* __restrict__ h,
                                                 const float* __restrict__ w,
                                                 u16* __restrict__ out16) {
  __shared__ float sh[4];
  __shared__ float sscale;
  const int row = blockIdx.x;
  const int tid = threadIdx.x;
  const float v = h[(size_t)row * DM + tid];
  float s = v * v;
#pragma unroll
  for (int off = 32; off; off >>= 1) s += __shfl_xor(s, off, 64);
  if ((tid & 63) == 0) sh[tid >> 6] = s;
  __syncthreads();
  if (tid == 0) {
    float t = sh[0] + sh[1] + sh[2] + sh[3];
    sscale = rsqrtf(t * (1.0f / DM) + 1e-5f);
  }
  __syncthreads();
  out16[(size_t)row * DM + tid] = f2bf(v * sscale * w[tid]);
}

// ---------------- causal depthwise conv (K=4) + bias + silu, bf16 in/out ----------------
__global__ __launch_bounds__(256) void conv_silu_k(const u16* __restrict__ xz16,
                                                   const float* __restrict__ cw,
                                                   const float* __restrict__ cb,
                                                   u16* __restrict__ out16) {
  const int idx = blockIdx.x * 256 + threadIdx.x;
  const int e = idx & (ED - 1);
  const int row = idx >> 9;
  const int t = row & (SEQ - 1);
  const float4 w = *(const float4*)(cw + e * 4);
  const u16* col = xz16 + e;
  float acc = cb[e];
  const float v0 = (t >= 3) ? bf2f(col[(size_t)(row - 3) * 1024]) : 0.f;
  const float v1 = (t >= 2) ? bf2f(col[(size_t)(row - 2) * 1024]) : 0.f;
  const float v2 = (t >= 1) ? bf2f(col[(size_t)(row - 1) * 1024]) : 0.f;
  const float v3 = bf2f(col[(size_t)row * 1024]);
  acc += v0 * w.x + v1 * w.y + v2 * w.z + v3 * w.w;
  out16[idx] = f2bf(silu_f(acc));
}

// ---------------- delta=softplus(...); pairs = pack(delta, delta*x) ----------------
__global__ __launch_bounds__(256) void dt_softplus_k(const float* __restrict__ dbc,
                                                     const float* __restrict__ dtw,
                                                     const float* __restrict__ dtb,
                                                     const u16* __restrict__ xbc16,
                                                     u32* __restrict__ pairs) {
  __shared__ float sdt[DTR];
  const int row = blockIdx.y;
  const int e = blockIdx.x * 256 + threadIdx.x;
  if (threadIdx.x < DTR) sdt[threadIdx.x] = dbc[(size_t)row * 48 + threadIdx.x];
  __syncthreads();
  const float* w = dtw + (size_t)e * DTR;
  float s = dtb[e];
#pragma unroll
  for (int r = 0; r < DTR; r++) s = fmaf(sdt[r], w[r], s);
  const float sp = fmaxf(s, 0.f) + log1pf(__expf(-fabsf(s)));
  const float xv = bf2f(xbc16[(size_t)row * ED + e]);
  pairs[(size_t)row * ED + e] = pack2(sp, sp * xv);
}

// ================= chunked selective scan =================
// pass1: local scan from h=0 -> hend16 (bf16), S=sum(delta) -> Sbuf.
__global__ __launch_bounds__(256) void scan_pass1(const u32* __restrict__ pairs,
                                                  const float* __restrict__ dbc,
                                                  u16* __restrict__ hend16,
                                                  float* __restrict__ Sbuf,
                                                  const float* __restrict__ A_log) {
  __shared__ float sB[LC][16];
  const int tid = threadIdx.x;
  const int e = blockIdx.x * 256 + tid;
  const int c = blockIdx.y;
  const int b = blockIdx.z;
  const int row0 = b * SEQ + c * LC;
  float Aen[16];
  {
    const float4* ap = (const float4*)(A_log + (size_t)e * 16);
#pragma unroll
    for (int q = 0; q < 4; q++) {
      float4 v = ap[q];
      Aen[4 * q + 0] = -__expf(v.x); Aen[4 * q + 1] = -__expf(v.y);
      Aen[4 * q + 2] = -__expf(v.z); Aen[4 * q + 3] = -__expf(v.w);
    }
  }
  for (int idx = tid; idx < LC * 16; idx += 256)
    sB[idx >> 4][idx & 15] = dbc[(size_t)(row0 + (idx >> 4)) * 48 + DTR + (idx & 15)];
  __syncthreads();
  const u32* pp = pairs + (size_t)row0 * ED + e;
  float h[16];
#pragma unroll
  for (int n = 0; n < 16; n++) h[n] = 0.f;
  float S = 0.f;
  u32 p = pp[0];
  for (int t = 0; t < LC; t++) {
    const u32 pn = (t + 1 < LC) ? pp[(size_t)(t + 1) * ED] : p;
    const float d = bf2f((u16)(p & 0xffff));
    const float dx = bf2f((u16)(p >> 16));
    S += d;
    const float4* bp = (const float4*)sB[t];
    const float4 B0 = bp[0], B1 = bp[1], B2 = bp[2], B3 = bp[3];
    const float Bv[16] = {B0.x, B0.y, B0.z, B0.w, B1.x, B1.y, B1.z, B1.w,
                          B2.x, B2.y, B2.z, B2.w, B3.x, B3.y, B3.z, B3.w};
#pragma unroll
    for (int n = 0; n < 16; n++) h[n] = __expf(d * Aen[n]) * h[n] + dx * Bv[n];
    p = pn;
  }
  u32 wbuf[8];
#pragma unroll
  for (int q = 0; q < 8; q++) wbuf[q] = pack2(h[2 * q], h[2 * q + 1]);
  u16* hp = hend16 + ((size_t)(c * BSZ + b) * ED + e) * 16;
  *(int4*)(hp) = *(int4*)&wbuf[0];
  *(int4*)(hp + 8) = *(int4*)&wbuf[4];
  Sbuf[(size_t)(c * BSZ + b) * ED + e] = S;
}

// mid: sequential over chunks; hend16 -> hin (exclusive prefix) in place.
__global__ __launch_bounds__(256) void scan_mid(u16* __restrict__ hend16,
                                                const float* __restrict__ Sbuf,
                                                const float* __restrict__ A_log) {
  const int idx = blockIdx.x * 256 + threadIdx.x; // B*ED*NST = 32768
  const int en = idx & 8191;
  const int b = idx >> 13;
  const int e = en >> 4;
  const float A = -__expf(A_log[en]);
  float h = 0.f;
#pragma unroll 4
  for (int c = 0; c < CH; c++) {
    const size_t base = (size_t)(c * BSZ + b) * 8192 + en;
    const float he = bf2f(hend16[base]);
    const float Sv = Sbuf[(size_t)(c * BSZ + b) * ED + e];
    hend16[base] = f2bf(h);
    h = __expf(A * Sv) * h + he;
  }
}

// pass2: re-scan from hin; y = C.h + D*x, gated by silu(z); y (bf16) -> xz x-half.
__global__ __launch_bounds__(256) void scan_pass2(const u32* __restrict__ pairs,
                                                  const u16* __restrict__ xbc16,
                                                  const float* __restrict__ dbc,
                                                  u16* __restrict__ xz16,
                                                  const u16* __restrict__ hin16,
                                                  const float* __restrict__ A_log,
                                                  const float* __restrict__ Dp) {
  __shared__ float sB[LC][16];
  __shared__ float sC[LC][16];
  const int tid = threadIdx.x;
  const int e = blockIdx.x * 256 + tid;
  const int c = blockIdx.y;
  const int b = blockIdx.z;
  const int row0 = b * SEQ + c * LC;
  float Aen[16];
  {
    const float4* ap = (const float4*)(A_log + (size_t)e * 16);
#pragma unroll
    for (int q = 0; q < 4; q++) {
      float4 v = ap[q];
      Aen[4 * q + 0] = -__expf(v.x); Aen[4 * q + 1] = -__expf(v.y);
      Aen[4 * q + 2] = -__expf(v.z); Aen[4 * q + 3] = -__expf(v.w);
    }
  }
  for (int idx = tid; idx < LC * 32; idx += 256) {
    const int i = idx >> 5, jj = idx & 31;
    const float v = dbc[(size_t)(row0 + i) * 48 + DTR + jj];
    if (jj < 16) sB[i][jj] = v; else sC[i][jj - 16] = v;
  }
  __syncthreads();
  float h[16];
  {
    const u16* hp = hin16 + ((size_t)(c * BSZ + b) * ED + e) * 16;
    int4 v0 = *(const int4*)(hp);
    int4 v1 = *(const int4*)(hp + 8);
    const u32* wv = (const u32*)&v0;
    const u32* wv1 = (const u32*)&v1;
#pragma unroll
    for (int q = 0; q < 4; q++) {
      h[2 * q] = bf2f((u16)(wv[q] & 0xffff));
      h[2 * q + 1] = bf2f((u16)(wv[q] >> 16));
      h[8 + 2 * q] = bf2f((u16)(wv1[q] & 0xffff));
      h[8 + 2 * q + 1] = bf2f((u16)(wv1[q] >> 16));
    }
  }
  const float De = Dp[e];
  const u32* pp = pairs + (size_t)row0 * ED + e;
  const u16* xp = xbc16 + (size_t)row0 * ED + e;
  const u16* zp = xz16 + (size_t)row0 * 1024 + ED + e;
  u16* yw = xz16 + (size_t)row0 * 1024 + e;
  u32 p = pp[0];
  float xv = bf2f(xp[0]);
  float zv = bf2f(zp[0]);
  for (int t = 0; t < LC; t++) {
    const int tn = (t + 1 < LC) ? t + 1 : t;
    const u32 pn = pp[(size_t)tn * ED];
    const float xnx = bf2f(xp[(size_t)tn * ED]);
    const float znx = bf2f(zp[(size_t)tn * 1024]);
    const float d = bf2f((u16)(p & 0xffff));
    const float dx = bf2f((u16)(p >> 16));
    const float4* bp = (const float4*)sB[t];
    const float4 B0 = bp[0], B1 = bp[1], B2 = bp[2], B3 = bp[3];
    const float Bv[16] = {B0.x, B0.y, B0.z, B0.w, B1.x, B1.y, B1.z, B1.w,
                          B2.x, B2.y, B2.z, B2.w, B3.x, B3.y, B3.z, B3.w};
    const float4* cp = (const float4*)sC[t];
    const float4 C0 = cp[0], C1 = cp[1], C2 = cp[2], C3 = cp[3];
    const float Cv[16] = {C0.x, C0.y, C0.z, C0.w, C1.x, C1.y, C1.z, C1.w,
                          C2.x, C2.y, C2.z, C2.w, C3.x, C3.y, C3.z, C3.w};
    float y0 = 0.f, y1 = 0.f, y2 = 0.f, y3 = 0.f;
#pragma unroll
    for (int n = 0; n < 16; n++) {
      h[n] = __expf(d * Aen[n]) * h[n] + dx * Bv[n];
      if ((n & 3) == 0) y0 = fmaf(h[n], Cv[n], y0);
      else if ((n & 3) == 1) y1 = fmaf(h[n], Cv[n], y1);
      else if ((n & 3) == 2) y2 = fmaf(h[n], Cv[n], y2);
      else y3 = fmaf(h[n], Cv[n], y3);
    }
    float y = ((y0 + y1) + (y2 + y3)) + De * xv;
    y *= silu_f(zv);
    yw[(size_t)t * 1024] = f2bf(y);
    p = pn; xv = xnx; zv = znx;
  }
}

// ---------------- final decode ----------------
__global__ __launch_bounds__(64) void decode_k(const float* __restrict__ h,
                                               const float* __restrict__ dw,
                                               const float* __restrict__ db,
                                               float* __restrict__ out) {
  const int b = blockIdx.x;
  const int tid = threadIdx.x;
  const float* row = h + ((size_t)b * SEQ + SEQ - 1) * DM;
  float s = 0.f;
  for (int i = tid; i < DM; i += 64) s = fmaf(row[i], dw[i], s);
#pragma unroll
  for (int off = 32; off; off >>= 1) s += __shfl_xor(s, off, 64);
  if (tid == 0) out[b] = 1.f / (1.f + __expf(-(s + db[0])));
}

extern "C" void kernel_launch(void* const* d_in, const int* in_sizes, int n_in,
                              void* d_out, int out_size, void* d_ws, size_t ws_size,
                              hipStream_t stream) {
  const float* x         = (const float*)d_in[0];
  const float* enc_w     = (const float*)d_in[1];
  const float* enc_b     = (const float*)d_in[2];
  const float* norm_w    = (const float*)d_in[3];
  const float* in_proj_w = (const float*)d_in[4];
  const float* conv_w    = (const float*)d_in[5];
  const float* conv_b    = (const float*)d_in[6];
  const float* x_proj_w  = (const float*)d_in[7];
  const float* dt_proj_w = (const float*)d_in[8];
  const float* dt_proj_b = (const float*)d_in[9];
  const float* A_log     = (const float*)d_in[10];
  const float* D_param   = (const float*)d_in[11];
  const float* out_proj_w= (const float*)d_in[12];
  const float* dec_w     = (const float*)d_in[13];
  const float* dec_b     = (const float*)d_in[14];
  float* out = (float*)d_out;

  float* ws = (float*)d_ws;
  float* h       = ws;                         // 2,097,152 f32
  u16*   xz16    = (u16*)(ws + 2097152);       // 8M u16 (4M f32 slots)
  u16*   xbc16   = (u16*)(ws + 6291456);       // 4M u16 (2M slots)
  u32*   pairs   = (u32*)(ws + 8388608);       // 4M u32
  float* dbc     = ws + 12582912;              // 393,216 f32
  u16*   hend16  = (u16*)(ws + 12976128);      // 2M u16 (1M slots)
  float* Sbuf    = ws + 14024704;              // 131,072 f32
  u16*   w16in   = (u16*)(ws + 14155776);      // 524,288 u16
  u16*   w16out  = (u16*)(ws + 14417920);      // 262,144 u16
  u16*   w16xp   = (u16*)(ws + 14548992);      // 49,152 u16
  u16*   normed16 = hend16;                    // aliased: disjoint lifetimes

  const dim3 blk(256);

  cvt_weights_k<<<(S_IN + S_OUT + S_XP + 255) / 256, blk, 0, stream>>>(
      in_proj_w, out_proj_w, x_proj_w, w16in, w16out, w16xp);

  gemm_nt_enc<<<dim3(DM / 64, MROWS / 64), blk, 0, stream>>>(
      x, enc_w, enc_b, h, MROWS, DM, INDIM, INDIM);

  for (int l = 0; l < 2; l++) {
    const float* Al = A_log + (size_t)l * ED * NST;
    rmsnorm_k<<<MROWS, 256, 0, stream>>>(h, norm_w + (size_t)l * DM, normed16);
    gemm_bf16_u16<<<dim3(1024 / 128, MROWS / 128), blk, 0, stream>>>(
        normed16, w16in + (size_t)l * 1024 * DM, xz16, MROWS, 1024, DM, DM, 1024);
    conv_silu_k<<<(MROWS * ED) / 256, blk, 0, stream>>>(
        xz16, conv_w + (size_t)l * ED * 4, conv_b + (size_t)l * ED, xbc16);
    gemm_bf16_f32<false><<<dim3(1, MROWS / 128), blk, 0, stream>>>(
        xbc16, w16xp + (size_t)l * 48 * ED, dbc, MROWS, 48, ED, ED, 48);
    dt_softplus_k<<<dim3(2, MROWS), blk, 0, stream>>>(
        dbc, dt_proj_w + (size_t)l * ED * DTR, dt_proj_b + (size_t)l * ED,
        xbc16, pairs);
    scan_pass1<<<dim3(ED / 256, CH, BSZ), blk, 0, stream>>>(
        pairs, dbc, hend16, Sbuf, Al);
    scan_mid<<<(BSZ * ED * NST) / 256, blk, 0, stream>>>(hend16, Sbuf, Al);
    scan_pass2<<<dim3(ED / 256, CH, BSZ), blk, 0, stream>>>(
        pairs, xbc16, dbc, xz16, hend16, Al, D_param + (size_t)l * ED);
    gemm_bf16_f32<true><<<dim3(DM / 128, MROWS / 128), blk, 0, stream>>>(
        xz16, w16out + (size_t)l * DM * ED, h, MROWS, DM, ED, 1024, DM);
  }

  decode_k<<<4, 64, 0, stream>>>(h, dec_w, dec_b, out);
}